// Round 12
// baseline (298.901 us; speedup 1.0000x reference)
//
#include <hip/hip_runtime.h>
#include <stdint.h>

// Problem constants
#define B 8
#define N 2048
#define D 16
#define KNN 32
#define DM 256
#define CAP 128  // candidate cap; approx-tau yields ~44 +/- 7 candidates (z~13)

// ---------------------------------------------------------------------------
// K1: fused prep (proven). xcrd stored TRANSPOSED [B][D][N] so knn_main's
// staging loads are lane-contiguous.  Block 64: W transpose + pe bias/loss.
// ---------------------------------------------------------------------------
__global__ __launch_bounds__(256) void knn_prep(
    const float* __restrict__ x, const float* __restrict__ features,
    const float* __restrict__ Wc, const float* __restrict__ Wf,
    const float* __restrict__ pec, const float* __restrict__ pef,
    float* __restrict__ xcrdT, float* __restrict__ sq,
    float* __restrict__ Tc, float* __restrict__ Tf,
    float* __restrict__ WcT, float* __restrict__ WfT,
    float* __restrict__ cbias, float* __restrict__ pe_loss_out)
{
    if (blockIdx.x == 64) {
        int dm = threadIdx.x;
        float cb = 0.f, al = 0.f;
#pragma unroll
        for (int p = 0; p < D; ++p)
            cb += pec[p * DM + dm] + pef[p * DM + dm];
#pragma unroll
        for (int p = 0; p < D; ++p)
            al += fabsf(pec[p * DM + dm]) + fabsf(pef[p * DM + dm]);
        cbias[dm] = cb;
#pragma unroll
        for (int k = 0; k < KNN; ++k) {
            WcT[k * DM + dm] = Wc[dm * KNN + k];
            WfT[k * DM + dm] = Wf[dm * KNN + k];
        }
        __shared__ float redf[256];
        redf[dm] = al; __syncthreads();
        for (int st = 128; st > 0; st >>= 1) {
            if (dm < st) redf[dm] += redf[dm + st];
            __syncthreads();
        }
        if (dm == 0) pe_loss_out[0] = redf[0];
        return;
    }

    int tid = threadIdx.x;
    int b = blockIdx.x >> 3;

    // ---- own-batch stats: 8 rows per thread, fp64 accumulate ----
    double ls[D], lq[D];
#pragma unroll
    for (int d = 0; d < D; ++d) { ls[d] = 0.0; lq[d] = 0.0; }
    for (int r = 0; r < 8; ++r) {
        const float* row = x + ((size_t)b * N + r * 256 + tid) * D;
#pragma unroll
        for (int d = 0; d < D; d += 4) {
            float4 v = *(const float4*)(row + d);
            double x0 = v.x, x1 = v.y, x2 = v.z, x3 = v.w;
            ls[d]   += x0; lq[d]   += x0 * x0;
            ls[d+1] += x1; lq[d+1] += x1 * x1;
            ls[d+2] += x2; lq[d+2] += x2 * x2;
            ls[d+3] += x3; lq[d+3] += x3 * x3;
        }
    }
#pragma unroll
    for (int d = 0; d < D; ++d) {
        double s = ls[d], q = lq[d];
#pragma unroll
        for (int st = 32; st >= 1; st >>= 1) {
            s += __shfl_xor(s, st, 64);
            q += __shfl_xor(q, st, 64);
        }
        ls[d] = s; lq[d] = q;
    }
    __shared__ double sred[4][2 * D];
    __shared__ float smean[32], sscale[32];
    int wave = tid >> 6, lane = tid & 63;
    if (lane == 0) {
#pragma unroll
        for (int d = 0; d < D; ++d) {
            sred[wave][d]     = ls[d];
            sred[wave][D + d] = lq[d];
        }
    }
    __syncthreads();
    if (tid < D) {
        int d = tid;
        double S = sred[0][d] + sred[1][d] + sred[2][d] + sred[3][d];
        double Q = sred[0][D+d] + sred[1][D+d] + sred[2][D+d] + sred[3][D+d];
        double mean = S / (double)N;
        double var  = (Q - S * S / (double)N) / (double)(N - 1);
        if (var < 0.0) var = 0.0;
        float stdv = (float)sqrt(var);
        float scl  = 1.0f / (stdv + 1e-5f);
        float scl0 = 1.0f / (0.0f + 1e-5f);
        bool mask = features[b * D + d] > 0.1f;
        smean [d]      = mask ? 0.0f : (float)mean;
        sscale[d]      = mask ? scl0 : scl;
        smean [16 + d] = mask ? (float)mean : 0.0f;
        sscale[16 + d] = mask ? scl : scl0;
    }
    __syncthreads();

    // ---- per-point processing (identical arithmetic; transposed store) ----
    int t = blockIdx.x * 256 + tid;
    int nn = t & (N - 1);
    float tc = 0.f, tf = 0.f, s = 0.f;
    float row[D];
#pragma unroll
    for (int d = 0; d < D; ++d) {
        float xv = x[(size_t)t * D + d];
        bool mask = features[b * D + d] > 0.1f;
        float xc = mask ? 0.f : xv;
        float xf = mask ? xv : 0.f;
        row[d] = xc;
        s += xc * xc;                            // sequential, mirrors ref sq
        float vc = (xc - smean[d])      * sscale[d];
        vc = fminf(10.f, fmaxf(-10.f, vc));
        float vf = (xf - smean[16 + d]) * sscale[16 + d];
        vf = fminf(10.f, fmaxf(-10.f, vf));
        tc += vc; tf += vf;
    }
#pragma unroll
    for (int d = 0; d < D; ++d)                  // coalesced per-d across wave
        xcrdT[((size_t)b * D + d) * N + nn] = row[d];
    sq[t] = s; Tc[t] = tc; Tf[t] = tf;
}

// ---------------------------------------------------------------------------
// K2: ROUND-12 -- round-10/11 proven LDS-panel structure (block = 4 waves =
// 8 queries, per-wave round-8 2-query pipeline) with DOUBLE-BUFFERED
// ASYNC STAGING (T14 issue-early/write-late):
//   half-tiles of 128 neighbors, tbuf[2][16][128] (8 KB each, total LDS
//   unchanged ~28 KB -> 5 blocks/CU).  Per half-tile:
//     {issue global loads ht+1 -> named regs} {compute ht from buf[ht&1]}
//     {vmcnt-forced ds_write buf[(ht+1)&1]} {__syncthreads}
//   One barrier per half-tile (16 total, same count as round 11) and the
//   L2 latency of staging hides under compute.  Single-barrier safety:
//   write(ht+1) targets the buffer last read by compute(ht-1), which all
//   waves finished before the ht-1 barrier.  sq is staged per half-tile
//   too (sqt[2][128]) removing 32 scalar global loads/wave.
// Partition m = (ht*2+jt)*64+lane == round-8's j*64+lane; dot sequential-d
// -> distances, keys, output bit-identical.
// ds_read tbuf[b][d][ml]: stride 4B -> 2 lanes/bank (free).  Staging
// ds_write_b128: exactly 8 words/bank -> conflict-free.
// Spill tripwire: WRITE_SIZE must stay 16384 KB.
// ---------------------------------------------------------------------------
#define WAVE_LDS_FENCE() do {                                   \
    asm volatile("s_waitcnt lgkmcnt(0)" ::: "memory");          \
    __builtin_amdgcn_sched_barrier(0);                          \
} while (0)

__global__ __launch_bounds__(256) void knn_main(
    const float* __restrict__ xcrdT, const float* __restrict__ sq,
    const float* __restrict__ Tc, const float* __restrict__ Tf,
    const float* __restrict__ WcT, const float* __restrict__ WfT,
    const float* __restrict__ cbias, float* __restrict__ out)
{
    __shared__ float tbuf[2][D][128];            // 2 x 8 KB half-tiles
    __shared__ float sqt[2][128];                // staged sq per half-tile
    __shared__ unsigned long long collect[8][CAP];
    __shared__ int sortedm[8][KNN];
    __shared__ float akbk[8][KNN][2];            // [q-slot][k][{a,b}]

    const int tid  = threadIdx.x;
    const int lane = tid & 63;
    const int wid  = tid >> 6;
    const int qid0 = blockIdx.x * 8 + wid * 2;   // even
    const int b  = qid0 >> 11;
    const int n0 = qid0 & (N - 1);
    const int n1 = n0 + 1;
    const int c0 = wid * 2, c1 = c0 + 1;         // this wave's LDS slots

    const float* xbT = xcrdT + (size_t)b * D * N;
    const float* sqb = sq + b * N;

    // two query rows (adjacent -> float2)
    float qx0[D], qx1[D];
#pragma unroll
    for (int d = 0; d < D; ++d) {
        float2 v = *(const float2*)(xbT + (size_t)d * N + n0);
        qx0[d] = v.x; qx1[d] = v.y;
    }
    const float sqn0 = sqb[n0], sqn1 = sqb[n1];

    // ---- fill: 16 half-tiles, double-buffered async staging ----
    const int d0 = tid >> 5;                     // 0..7 (stages d0 and d0+8)
    const int cc = tid & 31;                     // float4 column
    float4 rA, rB, rS;

#define STAGE_ISSUE(ht) do {                                            \
    const float* src_ = xbT + (size_t)d0 * N + (ht) * 128 + cc * 4;     \
    rA = *(const float4*)(src_);                                        \
    rB = *(const float4*)(src_ + (size_t)8 * N);                        \
    if (tid < 32) rS = *(const float4*)(sqb + (ht) * 128 + tid * 4);    \
} while (0)

#define STAGE_WRITE(ht) do {                                            \
    *(float4*)&tbuf[(ht) & 1][d0][cc * 4] = rA;                         \
    *(float4*)&tbuf[(ht) & 1][d0 + 8][cc * 4] = rB;                     \
    if (tid < 32) *(float4*)&sqt[(ht) & 1][tid * 4] = rS;               \
} while (0)

    float orig0[KNN], orig1[KNN];
    float vm0 = 1e30f, vm1 = 1e30f;

    STAGE_ISSUE(0);
    STAGE_WRITE(0);
    __syncthreads();

#pragma unroll
    for (int ht = 0; ht < 16; ++ht) {
        if (ht + 1 < 16) STAGE_ISSUE(ht + 1);
#pragma unroll
        for (int jt = 0; jt < 2; ++jt) {
            const int j  = ht * 2 + jt;          // same j as round 8
            const int ml = jt * 64 + lane;
            float dot0 = 0.f, dot1 = 0.f;
#pragma unroll
            for (int d = 0; d < D; ++d) {
                float v = tbuf[ht & 1][d][ml];
                dot0 += qx0[d] * v;
                dot1 += qx1[d] * v;
            }
            float sm = sqt[ht & 1][ml];
            float o0 = fabsf(sqrtf(fmaxf(sqn0 + sm - 2.0f * dot0, 0.f)));
            float o1 = fabsf(sqrtf(fmaxf(sqn1 + sm - 2.0f * dot1, 0.f)));
            orig0[j] = o0; orig1[j] = o1;
            vm0 = fminf(vm0, o0); vm1 = fminf(vm1, o1);
        }
        if (ht + 1 < 16) STAGE_WRITE(ht + 1);    // vmcnt here: hidden by compute
        __syncthreads();
    }

    // ---- approx tau per query: 32nd-smallest of the 64 per-lane minima ----
#pragma unroll
    for (int k = 2; k <= 64; k <<= 1) {
#pragma unroll
        for (int j = k >> 1; j >= 1; j >>= 1) {
            float o0 = __shfl_xor(vm0, j, 64);
            float o1 = __shfl_xor(vm1, j, 64);
            bool lower = (lane & j) == 0;
            bool up    = (lane & k) == 0;
            vm0 = (lower == up) ? fminf(vm0, o0) : fmaxf(vm0, o0);
            vm1 = (lower == up) ? fminf(vm1, o1) : fmaxf(vm1, o1);
        }
    }
    const float tau0 = __shfl(vm0, 31, 64);      // >= exact 32nd smallest (q0)
    const float tau1 = __shfl(vm1, 31, 64);      // >= exact 32nd smallest (q1)

    // ---- tie-fixup compact, per query (wave-private LDS slice) ----
    const unsigned long long lmask = (1ULL << lane) - 1ULL;
    int T0, T1;
    {
        int base = 0;
#pragma unroll
        for (int j = 0; j < KNN; ++j) {
            bool f = (orig0[j] <= tau0);
            unsigned long long mk = __ballot(f);
            if (f) {
                int pos = base + (int)__popcll(mk & lmask);
                if (pos < CAP)
                    collect[c0][pos] =
                        (((unsigned long long)__float_as_uint(orig0[j])) << 11)
                        | (unsigned)(j * 64 + lane);
            }
            base += (int)__popcll(mk);
        }
        T0 = base < CAP ? base : CAP;
    }
    {
        int base = 0;
#pragma unroll
        for (int j = 0; j < KNN; ++j) {
            bool f = (orig1[j] <= tau1);
            unsigned long long mk = __ballot(f);
            if (f) {
                int pos = base + (int)__popcll(mk & lmask);
                if (pos < CAP)
                    collect[c1][pos] =
                        (((unsigned long long)__float_as_uint(orig1[j])) << 11)
                        | (unsigned)(j * 64 + lane);
            }
            base += (int)__popcll(mk);
        }
        T1 = base < CAP ? base : CAP;
    }
    WAVE_LDS_FENCE();                            // own-wave ds_writes drained

    if (T0 <= 64 && T1 <= 64) {
        // ---- fast path: two interleaved in-wave 64-key bitonic sorts ----
        unsigned long long key0 = (lane < T0) ? collect[c0][lane] : ~0ULL;
        unsigned long long key1 = (lane < T1) ? collect[c1][lane] : ~0ULL;
#pragma unroll
        for (int k = 2; k <= 64; k <<= 1) {
#pragma unroll
            for (int j = k >> 1; j >= 1; j >>= 1) {
                unsigned long long o0 = __shfl_xor(key0, j, 64);
                unsigned long long o1 = __shfl_xor(key1, j, 64);
                bool lower = (lane & j) == 0;
                bool up    = (lane & k) == 0;
                unsigned long long mn0 = (o0 < key0) ? o0 : key0;
                unsigned long long mx0 = (o0 < key0) ? key0 : o0;
                unsigned long long mn1 = (o1 < key1) ? o1 : key1;
                unsigned long long mx1 = (o1 < key1) ? key1 : o1;
                key0 = (lower == up) ? mn0 : mx0;
                key1 = (lower == up) ? mn1 : mx1;
            }
        }
        if (lane < KNN) {
            sortedm[c0][lane] = (int)(key0 & 2047u);
            sortedm[c1][lane] = (int)(key1 & 2047u);
        }
    } else {
        // ---- rare path: per-query fast/slow handling ----
#pragma unroll 1
        for (int q = 0; q < 2; ++q) {
            int T = q ? T1 : T0;
            unsigned long long* co = collect[q ? c1 : c0];
            int* so = sortedm[q ? c1 : c0];
            if (T <= 64) {
                unsigned long long key = (lane < T) ? co[lane] : ~0ULL;
#pragma unroll
                for (int k = 2; k <= 64; k <<= 1) {
#pragma unroll
                    for (int j = k >> 1; j >= 1; j >>= 1) {
                        unsigned long long o = __shfl_xor(key, j, 64);
                        bool lower = (lane & j) == 0;
                        bool up    = (lane & k) == 0;
                        unsigned long long mn = (o < key) ? o : key;
                        unsigned long long mx = (o < key) ? key : o;
                        key = (lower == up) ? mn : mx;
                    }
                }
                if (lane < KNN) so[lane] = (int)(key & 2047u);
            } else {
#pragma unroll 1
                for (int slot = 0; slot < CAP / 64; ++slot) {
                    int i = lane + slot * 64;
                    if (i < T) {
                        unsigned long long mk = co[i];
                        int rank = 0;
#pragma unroll 4
                        for (int t2 = 0; t2 < T; ++t2)
                            rank += (co[t2] < mk) ? 1 : 0;
                        if (rank < KNN) so[rank] = (int)(mk & 2047u);
                    }
                }
            }
        }
    }
    WAVE_LDS_FENCE();                            // sortedm visible to own wave

    // ---- gather ak/bk lane-parallel: lane = (q,k) ----
    const float* Tcb = Tc + b * N;
    const float* Tfb = Tf + b * N;
    {
        const float Tcn0 = Tcb[n0], Tfn0 = Tfb[n0];
        const float Tcn1 = Tcb[n1], Tfn1 = Tfb[n1];
        int q = lane >> 5;                       // 0 or 1
        int k = lane & 31;
        int wm = sortedm[c0 + q][k];
        float av = Tcb[wm] - (q ? Tcn1 : Tcn0);
        float bv = Tfb[wm] - (q ? Tfn1 : Tfn0);
        akbk[c0 + q][k][0] = av;
        akbk[c0 + q][k][1] = bv;
    }
    WAVE_LDS_FENCE();                            // akbk visible to own wave

    // ---- matvec: W loads shared by both queries; ak/bk from LDS bcast ----
    float acc0[4] = {0.f, 0.f, 0.f, 0.f};
    float acc1[4] = {0.f, 0.f, 0.f, 0.f};

#pragma unroll
    for (int k = 0; k < KNN; ++k) {
        float ak0 = akbk[c0][k][0], bk0 = akbk[c0][k][1];
        float ak1 = akbk[c1][k][0], bk1 = akbk[c1][k][1];
        const float* wc = WcT + k * DM + lane;
        const float* wf = WfT + k * DM + lane;
#pragma unroll
        for (int q = 0; q < 4; ++q) {
            float wcv = wc[q * 64];
            float wfv = wf[q * 64];
            acc0[q] += wcv * ak0 + wfv * bk0;
            acc1[q] += wcv * ak1 + wfv * bk1;
        }
    }

    size_t ob0 = (size_t)qid0 * DM + lane;
#pragma unroll
    for (int q = 0; q < 4; ++q) {
        float cb = cbias[lane + q * 64];
        out[ob0 + q * 64]      = acc0[q] + cb;
        out[ob0 + DM + q * 64] = acc1[q] + cb;
    }
}

// ---------------------------------------------------------------------------
extern "C" void kernel_launch(void* const* d_in, const int* in_sizes, int n_in,
                              void* d_out, int out_size, void* d_ws, size_t ws_size,
                              hipStream_t stream)
{
    const float* x        = (const float*)d_in[0];   // (B,N,D)
    const float* features = (const float*)d_in[1];   // (B,D)
    const float* W_crd    = (const float*)d_in[2];   // (DM,K)
    const float* W_ftr    = (const float*)d_in[3];   // (DM,K)
    const float* pe_crd   = (const float*)d_in[4];   // (1,1,D,DM)
    const float* pe_ftr   = (const float*)d_in[5];   // (1,1,D,DM)
    // d_in[6] = k (constant 32), ignored

    float* out = (float*)d_out;                      // B*N*DM floats + 1 (pe_loss)

    float* xcrdT = (float*)d_ws;                     // 262144 (B*D*N, transposed)
    float* sqv   = xcrdT + (size_t)B * N * D;        // 16384
    float* Tc    = sqv  + B * N;                     // 16384
    float* Tf    = Tc   + B * N;                     // 16384
    float* cbias = Tf   + B * N;                     // 256
    float* WcT   = cbias + DM;                       // 8192
    float* WfT   = WcT + KNN * DM;                   // 8192

    knn_prep<<<65, 256, 0, stream>>>(x, features, W_crd, W_ftr, pe_crd, pe_ftr,
                                     xcrdT, sqv, Tc, Tf, WcT, WfT, cbias,
                                     out + (size_t)out_size - 1);
    knn_main<<<(B * N) / 8, 256, 0, stream>>>(xcrdT, sqv, Tc, Tf,
                                              WcT, WfT, cbias, out);
}

// Round 13
// 165.464 us; speedup vs baseline: 1.8064x; 1.8064x over previous
//
#include <hip/hip_runtime.h>
#include <stdint.h>

// Problem constants
#define B 8
#define N 2048
#define D 16
#define KNN 32
#define DM 256
#define CAP 128  // candidate cap; approx-tau yields ~44 +/- 7 candidates (z~13)

// ---------------------------------------------------------------------------
// K1: fused prep (proven). xcrd stored TRANSPOSED [B][D][N] so knn_main's
// staging loads are lane-contiguous.  Block 64: W transpose + pe bias/loss.
// ---------------------------------------------------------------------------
__global__ __launch_bounds__(256) void knn_prep(
    const float* __restrict__ x, const float* __restrict__ features,
    const float* __restrict__ Wc, const float* __restrict__ Wf,
    const float* __restrict__ pec, const float* __restrict__ pef,
    float* __restrict__ xcrdT, float* __restrict__ sq,
    float* __restrict__ Tc, float* __restrict__ Tf,
    float* __restrict__ WcT, float* __restrict__ WfT,
    float* __restrict__ cbias, float* __restrict__ pe_loss_out)
{
    if (blockIdx.x == 64) {
        int dm = threadIdx.x;
        float cb = 0.f, al = 0.f;
#pragma unroll
        for (int p = 0; p < D; ++p)
            cb += pec[p * DM + dm] + pef[p * DM + dm];
#pragma unroll
        for (int p = 0; p < D; ++p)
            al += fabsf(pec[p * DM + dm]) + fabsf(pef[p * DM + dm]);
        cbias[dm] = cb;
#pragma unroll
        for (int k = 0; k < KNN; ++k) {
            WcT[k * DM + dm] = Wc[dm * KNN + k];
            WfT[k * DM + dm] = Wf[dm * KNN + k];
        }
        __shared__ float redf[256];
        redf[dm] = al; __syncthreads();
        for (int st = 128; st > 0; st >>= 1) {
            if (dm < st) redf[dm] += redf[dm + st];
            __syncthreads();
        }
        if (dm == 0) pe_loss_out[0] = redf[0];
        return;
    }

    int tid = threadIdx.x;
    int b = blockIdx.x >> 3;

    // ---- own-batch stats: 8 rows per thread, fp64 accumulate ----
    double ls[D], lq[D];
#pragma unroll
    for (int d = 0; d < D; ++d) { ls[d] = 0.0; lq[d] = 0.0; }
    for (int r = 0; r < 8; ++r) {
        const float* row = x + ((size_t)b * N + r * 256 + tid) * D;
#pragma unroll
        for (int d = 0; d < D; d += 4) {
            float4 v = *(const float4*)(row + d);
            double x0 = v.x, x1 = v.y, x2 = v.z, x3 = v.w;
            ls[d]   += x0; lq[d]   += x0 * x0;
            ls[d+1] += x1; lq[d+1] += x1 * x1;
            ls[d+2] += x2; lq[d+2] += x2 * x2;
            ls[d+3] += x3; lq[d+3] += x3 * x3;
        }
    }
#pragma unroll
    for (int d = 0; d < D; ++d) {
        double s = ls[d], q = lq[d];
#pragma unroll
        for (int st = 32; st >= 1; st >>= 1) {
            s += __shfl_xor(s, st, 64);
            q += __shfl_xor(q, st, 64);
        }
        ls[d] = s; lq[d] = q;
    }
    __shared__ double sred[4][2 * D];
    __shared__ float smean[32], sscale[32];
    int wave = tid >> 6, lane = tid & 63;
    if (lane == 0) {
#pragma unroll
        for (int d = 0; d < D; ++d) {
            sred[wave][d]     = ls[d];
            sred[wave][D + d] = lq[d];
        }
    }
    __syncthreads();
    if (tid < D) {
        int d = tid;
        double S = sred[0][d] + sred[1][d] + sred[2][d] + sred[3][d];
        double Q = sred[0][D+d] + sred[1][D+d] + sred[2][D+d] + sred[3][D+d];
        double mean = S / (double)N;
        double var  = (Q - S * S / (double)N) / (double)(N - 1);
        if (var < 0.0) var = 0.0;
        float stdv = (float)sqrt(var);
        float scl  = 1.0f / (stdv + 1e-5f);
        float scl0 = 1.0f / (0.0f + 1e-5f);
        bool mask = features[b * D + d] > 0.1f;
        smean [d]      = mask ? 0.0f : (float)mean;
        sscale[d]      = mask ? scl0 : scl;
        smean [16 + d] = mask ? (float)mean : 0.0f;
        sscale[16 + d] = mask ? scl : scl0;
    }
    __syncthreads();

    // ---- per-point processing (identical arithmetic; transposed store) ----
    int t = blockIdx.x * 256 + tid;
    int nn = t & (N - 1);
    float tc = 0.f, tf = 0.f, s = 0.f;
    float row[D];
#pragma unroll
    for (int d = 0; d < D; ++d) {
        float xv = x[(size_t)t * D + d];
        bool mask = features[b * D + d] > 0.1f;
        float xc = mask ? 0.f : xv;
        float xf = mask ? xv : 0.f;
        row[d] = xc;
        s += xc * xc;                            // sequential, mirrors ref sq
        float vc = (xc - smean[d])      * sscale[d];
        vc = fminf(10.f, fmaxf(-10.f, vc));
        float vf = (xf - smean[16 + d]) * sscale[16 + d];
        vf = fminf(10.f, fmaxf(-10.f, vf));
        tc += vc; tf += vf;
    }
#pragma unroll
    for (int d = 0; d < D; ++d)                  // coalesced per-d across wave
        xcrdT[((size_t)b * D + d) * N + nn] = row[d];
    sq[t] = s; Tc[t] = tc; Tf[t] = tf;
}

// ---------------------------------------------------------------------------
// K2: ROUND-13 -- round-11 PROVEN structure (block = 4 waves = 8 queries,
// per-wave round-8 2-query pipeline, LDS panel tiles) with the staging
// converted to DOUBLE-BUFFERED ASYNC DMA via global_load_lds:
//   - tbuf[2][16][256] (2 x 16 KB).  Wave wid stages row d = wid*4+dd of
//     tile t+1 with one global_load_lds(width 16) per row: LDS dest =
//     wave-uniform row base + lane*16 (the HW pattern), global src =
//     per-lane xbT + d*N + (t+1)*256 + lane*4.  NO VGPR round-trip, so the
//     round-12 register-liveness explosion cannot recur.
//   - one __syncthreads per tile (8 barriers vs r11's 16); hipcc emits
//     s_waitcnt vmcnt(0) lgkmcnt(0) before s_barrier, which both drains
//     the DMA (RAW) and orders the buffer swap (WAR: stage(t+1) writes the
//     buffer last read in compute(t-1), separated by the t-1 barrier).
//   - staging L2 latency lands under compute(t) (~500 cy of ds_read+VALU).
// Distances, partition m=(t*4+jt)*64+lane, keys, output: bit-identical to
// rounds 8/11.  Spill tripwire: WRITE_SIZE must stay 16384 KB.
// ---------------------------------------------------------------------------
#define WAVE_LDS_FENCE() do {                                   \
    asm volatile("s_waitcnt lgkmcnt(0)" ::: "memory");          \
    __builtin_amdgcn_sched_barrier(0);                          \
} while (0)

#define ASYNC_CP16(dst, src)                                            \
    __builtin_amdgcn_global_load_lds(                                   \
        (const __attribute__((address_space(1))) unsigned int*)(src),   \
        (__attribute__((address_space(3))) unsigned int*)(dst), 16, 0, 0)

__global__ __launch_bounds__(256) void knn_main(
    const float* __restrict__ xcrdT, const float* __restrict__ sq,
    const float* __restrict__ Tc, const float* __restrict__ Tf,
    const float* __restrict__ WcT, const float* __restrict__ WfT,
    const float* __restrict__ cbias, float* __restrict__ out)
{
    __shared__ float tbuf[2][D][256];            // 2 x 16 KB panel tiles
    __shared__ unsigned long long collect[8][CAP];
    __shared__ int sortedm[8][KNN];
    __shared__ float akbk[8][KNN][2];            // [q-slot][k][{a,b}]

    const int tid  = threadIdx.x;
    const int lane = tid & 63;
    const int wid  = tid >> 6;
    const int qid0 = blockIdx.x * 8 + wid * 2;   // even
    const int b  = qid0 >> 11;
    const int n0 = qid0 & (N - 1);
    const int n1 = n0 + 1;
    const int c0 = wid * 2, c1 = c0 + 1;         // this wave's LDS slots

    const float* xbT = xcrdT + (size_t)b * D * N;
    const float* sqb = sq + b * N;

    // two query rows (adjacent -> float2)
    float qx0[D], qx1[D];
#pragma unroll
    for (int d = 0; d < D; ++d) {
        float2 v = *(const float2*)(xbT + (size_t)d * N + n0);
        qx0[d] = v.x; qx1[d] = v.y;
    }
    const float sqn0 = sqb[n0], sqn1 = sqb[n1];

    // ---- fill: 8 tiles, double-buffered async-DMA staging ----
#define STAGE_DMA(t) do {                                               \
    _Pragma("unroll")                                                   \
    for (int dd = 0; dd < 4; ++dd) {                                    \
        const int d_ = wid * 4 + dd;                                    \
        ASYNC_CP16(&tbuf[(t) & 1][d_][0],                               \
                   xbT + (size_t)d_ * N + (t) * 256 + lane * 4);        \
    }                                                                   \
} while (0)

    float orig0[KNN], orig1[KNN];
    float vm0 = 1e30f, vm1 = 1e30f;

    STAGE_DMA(0);
    __syncthreads();                             // drains vmcnt(0): tile 0 ready

#pragma unroll
    for (int t = 0; t < 8; ++t) {
        if (t + 1 < 8) STAGE_DMA(t + 1);         // async into other buffer
#pragma unroll
        for (int jt = 0; jt < 4; ++jt) {
            const int j  = t * 4 + jt;           // same j as round 8
            const int ml = jt * 64 + lane;       // m = j*64+lane (identical)
            float dot0 = 0.f, dot1 = 0.f;
#pragma unroll
            for (int d = 0; d < D; ++d) {
                float v = tbuf[t & 1][d][ml];
                dot0 += qx0[d] * v;
                dot1 += qx1[d] * v;
            }
            float sm = sqb[t * 256 + ml];
            float o0 = fabsf(sqrtf(fmaxf(sqn0 + sm - 2.0f * dot0, 0.f)));
            float o1 = fabsf(sqrtf(fmaxf(sqn1 + sm - 2.0f * dot1, 0.f)));
            orig0[j] = o0; orig1[j] = o1;
            vm0 = fminf(vm0, o0); vm1 = fminf(vm1, o1);
        }
        __syncthreads();                         // drains DMA + swaps buffers
    }

    // ---- approx tau per query: 32nd-smallest of the 64 per-lane minima ----
#pragma unroll
    for (int k = 2; k <= 64; k <<= 1) {
#pragma unroll
        for (int j = k >> 1; j >= 1; j >>= 1) {
            float o0 = __shfl_xor(vm0, j, 64);
            float o1 = __shfl_xor(vm1, j, 64);
            bool lower = (lane & j) == 0;
            bool up    = (lane & k) == 0;
            vm0 = (lower == up) ? fminf(vm0, o0) : fmaxf(vm0, o0);
            vm1 = (lower == up) ? fminf(vm1, o1) : fmaxf(vm1, o1);
        }
    }
    const float tau0 = __shfl(vm0, 31, 64);      // >= exact 32nd smallest (q0)
    const float tau1 = __shfl(vm1, 31, 64);      // >= exact 32nd smallest (q1)

    // ---- tie-fixup compact, per query (wave-private LDS slice) ----
    const unsigned long long lmask = (1ULL << lane) - 1ULL;
    int T0, T1;
    {
        int base = 0;
#pragma unroll
        for (int j = 0; j < KNN; ++j) {
            bool f = (orig0[j] <= tau0);
            unsigned long long mk = __ballot(f);
            if (f) {
                int pos = base + (int)__popcll(mk & lmask);
                if (pos < CAP)
                    collect[c0][pos] =
                        (((unsigned long long)__float_as_uint(orig0[j])) << 11)
                        | (unsigned)(j * 64 + lane);
            }
            base += (int)__popcll(mk);
        }
        T0 = base < CAP ? base : CAP;
    }
    {
        int base = 0;
#pragma unroll
        for (int j = 0; j < KNN; ++j) {
            bool f = (orig1[j] <= tau1);
            unsigned long long mk = __ballot(f);
            if (f) {
                int pos = base + (int)__popcll(mk & lmask);
                if (pos < CAP)
                    collect[c1][pos] =
                        (((unsigned long long)__float_as_uint(orig1[j])) << 11)
                        | (unsigned)(j * 64 + lane);
            }
            base += (int)__popcll(mk);
        }
        T1 = base < CAP ? base : CAP;
    }
    WAVE_LDS_FENCE();                            // own-wave ds_writes drained

    if (T0 <= 64 && T1 <= 64) {
        // ---- fast path: two interleaved in-wave 64-key bitonic sorts ----
        unsigned long long key0 = (lane < T0) ? collect[c0][lane] : ~0ULL;
        unsigned long long key1 = (lane < T1) ? collect[c1][lane] : ~0ULL;
#pragma unroll
        for (int k = 2; k <= 64; k <<= 1) {
#pragma unroll
            for (int j = k >> 1; j >= 1; j >>= 1) {
                unsigned long long o0 = __shfl_xor(key0, j, 64);
                unsigned long long o1 = __shfl_xor(key1, j, 64);
                bool lower = (lane & j) == 0;
                bool up    = (lane & k) == 0;
                unsigned long long mn0 = (o0 < key0) ? o0 : key0;
                unsigned long long mx0 = (o0 < key0) ? key0 : o0;
                unsigned long long mn1 = (o1 < key1) ? o1 : key1;
                unsigned long long mx1 = (o1 < key1) ? key1 : o1;
                key0 = (lower == up) ? mn0 : mx0;
                key1 = (lower == up) ? mn1 : mx1;
            }
        }
        if (lane < KNN) {
            sortedm[c0][lane] = (int)(key0 & 2047u);
            sortedm[c1][lane] = (int)(key1 & 2047u);
        }
    } else {
        // ---- rare path: per-query fast/slow handling ----
#pragma unroll 1
        for (int q = 0; q < 2; ++q) {
            int T = q ? T1 : T0;
            unsigned long long* co = collect[q ? c1 : c0];
            int* so = sortedm[q ? c1 : c0];
            if (T <= 64) {
                unsigned long long key = (lane < T) ? co[lane] : ~0ULL;
#pragma unroll
                for (int k = 2; k <= 64; k <<= 1) {
#pragma unroll
                    for (int j = k >> 1; j >= 1; j >>= 1) {
                        unsigned long long o = __shfl_xor(key, j, 64);
                        bool lower = (lane & j) == 0;
                        bool up    = (lane & k) == 0;
                        unsigned long long mn = (o < key) ? o : key;
                        unsigned long long mx = (o < key) ? key : o;
                        key = (lower == up) ? mn : mx;
                    }
                }
                if (lane < KNN) so[lane] = (int)(key & 2047u);
            } else {
#pragma unroll 1
                for (int slot = 0; slot < CAP / 64; ++slot) {
                    int i = lane + slot * 64;
                    if (i < T) {
                        unsigned long long mk = co[i];
                        int rank = 0;
#pragma unroll 4
                        for (int t2 = 0; t2 < T; ++t2)
                            rank += (co[t2] < mk) ? 1 : 0;
                        if (rank < KNN) so[rank] = (int)(mk & 2047u);
                    }
                }
            }
        }
    }
    WAVE_LDS_FENCE();                            // sortedm visible to own wave

    // ---- gather ak/bk lane-parallel: lane = (q,k) ----
    const float* Tcb = Tc + b * N;
    const float* Tfb = Tf + b * N;
    {
        const float Tcn0 = Tcb[n0], Tfn0 = Tfb[n0];
        const float Tcn1 = Tcb[n1], Tfn1 = Tfb[n1];
        int q = lane >> 5;                       // 0 or 1
        int k = lane & 31;
        int wm = sortedm[c0 + q][k];
        float av = Tcb[wm] - (q ? Tcn1 : Tcn0);
        float bv = Tfb[wm] - (q ? Tfn1 : Tfn0);
        akbk[c0 + q][k][0] = av;
        akbk[c0 + q][k][1] = bv;
    }
    WAVE_LDS_FENCE();                            // akbk visible to own wave

    // ---- matvec: W loads shared by both queries; ak/bk from LDS bcast ----
    float acc0[4] = {0.f, 0.f, 0.f, 0.f};
    float acc1[4] = {0.f, 0.f, 0.f, 0.f};

#pragma unroll
    for (int k = 0; k < KNN; ++k) {
        float ak0 = akbk[c0][k][0], bk0 = akbk[c0][k][1];
        float ak1 = akbk[c1][k][0], bk1 = akbk[c1][k][1];
        const float* wc = WcT + k * DM + lane;
        const float* wf = WfT + k * DM + lane;
#pragma unroll
        for (int q = 0; q < 4; ++q) {
            float wcv = wc[q * 64];
            float wfv = wf[q * 64];
            acc0[q] += wcv * ak0 + wfv * bk0;
            acc1[q] += wcv * ak1 + wfv * bk1;
        }
    }

    size_t ob0 = (size_t)qid0 * DM + lane;
#pragma unroll
    for (int q = 0; q < 4; ++q) {
        float cb = cbias[lane + q * 64];
        out[ob0 + q * 64]      = acc0[q] + cb;
        out[ob0 + DM + q * 64] = acc1[q] + cb;
    }
}

// ---------------------------------------------------------------------------
extern "C" void kernel_launch(void* const* d_in, const int* in_sizes, int n_in,
                              void* d_out, int out_size, void* d_ws, size_t ws_size,
                              hipStream_t stream)
{
    const float* x        = (const float*)d_in[0];   // (B,N,D)
    const float* features = (const float*)d_in[1];   // (B,D)
    const float* W_crd    = (const float*)d_in[2];   // (DM,K)
    const float* W_ftr    = (const float*)d_in[3];   // (DM,K)
    const float* pe_crd   = (const float*)d_in[4];   // (1,1,D,DM)
    const float* pe_ftr   = (const float*)d_in[5];   // (1,1,D,DM)
    // d_in[6] = k (constant 32), ignored

    float* out = (float*)d_out;                      // B*N*DM floats + 1 (pe_loss)

    float* xcrdT = (float*)d_ws;                     // 262144 (B*D*N, transposed)
    float* sqv   = xcrdT + (size_t)B * N * D;        // 16384
    float* Tc    = sqv  + B * N;                     // 16384
    float* Tf    = Tc   + B * N;                     // 16384
    float* cbias = Tf   + B * N;                     // 256
    float* WcT   = cbias + DM;                       // 8192
    float* WfT   = WcT + KNN * DM;                   // 8192

    knn_prep<<<65, 256, 0, stream>>>(x, features, W_crd, W_ftr, pe_crd, pe_ftr,
                                     xcrdT, sqv, Tc, Tf, WcT, WfT, cbias,
                                     out + (size_t)out_size - 1);
    knn_main<<<(B * N) / 8, 256, 0, stream>>>(xcrdT, sqv, Tc, Tf,
                                              WcT, WfT, cbias, out);
}

// Round 14
// 153.106 us; speedup vs baseline: 1.9522x; 1.0807x over previous
//
#include <hip/hip_runtime.h>
#include <stdint.h>

// Problem constants
#define B 8
#define N 2048
#define D 16
#define KNN 32
#define DM 256
#define CAP 128  // candidate cap; approx-tau yields ~44 +/- 7 candidates (z~13)

// ---------------------------------------------------------------------------
// K1: fused prep (proven). xcrd stored TRANSPOSED [B][D][N].  ROUND-14: W is
// written in an INTERLEAVED float4 layout: WcT4[k*256 + (dm&63)*4 + (dm>>6)]
// so knn_main's matvec reads one dwordx4 per (k, c/f) instead of 4 dwords.
// Block 64: pe bias/loss verbatim.
// ---------------------------------------------------------------------------
__global__ __launch_bounds__(256) void knn_prep(
    const float* __restrict__ x, const float* __restrict__ features,
    const float* __restrict__ Wc, const float* __restrict__ Wf,
    const float* __restrict__ pec, const float* __restrict__ pef,
    float* __restrict__ xcrdT, float* __restrict__ sq,
    float* __restrict__ Tc, float* __restrict__ Tf,
    float* __restrict__ WcT, float* __restrict__ WfT,
    float* __restrict__ cbias, float* __restrict__ pe_loss_out)
{
    if (blockIdx.x == 64) {
        int dm = threadIdx.x;
        float cb = 0.f, al = 0.f;
#pragma unroll
        for (int p = 0; p < D; ++p)
            cb += pec[p * DM + dm] + pef[p * DM + dm];
#pragma unroll
        for (int p = 0; p < D; ++p)
            al += fabsf(pec[p * DM + dm]) + fabsf(pef[p * DM + dm]);
        cbias[dm] = cb;
#pragma unroll
        for (int k = 0; k < KNN; ++k) {
            int pos = k * DM + (dm & 63) * 4 + (dm >> 6);   // float4-interleaved
            WcT[pos] = Wc[dm * KNN + k];
            WfT[pos] = Wf[dm * KNN + k];
        }
        __shared__ float redf[256];
        redf[dm] = al; __syncthreads();
        for (int st = 128; st > 0; st >>= 1) {
            if (dm < st) redf[dm] += redf[dm + st];
            __syncthreads();
        }
        if (dm == 0) pe_loss_out[0] = redf[0];
        return;
    }

    int tid = threadIdx.x;
    int b = blockIdx.x >> 3;

    // ---- own-batch stats: 8 rows per thread, fp64 accumulate ----
    double ls[D], lq[D];
#pragma unroll
    for (int d = 0; d < D; ++d) { ls[d] = 0.0; lq[d] = 0.0; }
    for (int r = 0; r < 8; ++r) {
        const float* row = x + ((size_t)b * N + r * 256 + tid) * D;
#pragma unroll
        for (int d = 0; d < D; d += 4) {
            float4 v = *(const float4*)(row + d);
            double x0 = v.x, x1 = v.y, x2 = v.z, x3 = v.w;
            ls[d]   += x0; lq[d]   += x0 * x0;
            ls[d+1] += x1; lq[d+1] += x1 * x1;
            ls[d+2] += x2; lq[d+2] += x2 * x2;
            ls[d+3] += x3; lq[d+3] += x3 * x3;
        }
    }
#pragma unroll
    for (int d = 0; d < D; ++d) {
        double s = ls[d], q = lq[d];
#pragma unroll
        for (int st = 32; st >= 1; st >>= 1) {
            s += __shfl_xor(s, st, 64);
            q += __shfl_xor(q, st, 64);
        }
        ls[d] = s; lq[d] = q;
    }
    __shared__ double sred[4][2 * D];
    __shared__ float smean[32], sscale[32];
    int wave = tid >> 6, lane = tid & 63;
    if (lane == 0) {
#pragma unroll
        for (int d = 0; d < D; ++d) {
            sred[wave][d]     = ls[d];
            sred[wave][D + d] = lq[d];
        }
    }
    __syncthreads();
    if (tid < D) {
        int d = tid;
        double S = sred[0][d] + sred[1][d] + sred[2][d] + sred[3][d];
        double Q = sred[0][D+d] + sred[1][D+d] + sred[2][D+d] + sred[3][D+d];
        double mean = S / (double)N;
        double var  = (Q - S * S / (double)N) / (double)(N - 1);
        if (var < 0.0) var = 0.0;
        float stdv = (float)sqrt(var);
        float scl  = 1.0f / (stdv + 1e-5f);
        float scl0 = 1.0f / (0.0f + 1e-5f);
        bool mask = features[b * D + d] > 0.1f;
        smean [d]      = mask ? 0.0f : (float)mean;
        sscale[d]      = mask ? scl0 : scl;
        smean [16 + d] = mask ? (float)mean : 0.0f;
        sscale[16 + d] = mask ? scl : scl0;
    }
    __syncthreads();

    // ---- per-point processing (identical arithmetic; transposed store) ----
    int t = blockIdx.x * 256 + tid;
    int nn = t & (N - 1);
    float tc = 0.f, tf = 0.f, s = 0.f;
    float row[D];
#pragma unroll
    for (int d = 0; d < D; ++d) {
        float xv = x[(size_t)t * D + d];
        bool mask = features[b * D + d] > 0.1f;
        float xc = mask ? 0.f : xv;
        float xf = mask ? xv : 0.f;
        row[d] = xc;
        s += xc * xc;                            // sequential, mirrors ref sq
        float vc = (xc - smean[d])      * sscale[d];
        vc = fminf(10.f, fmaxf(-10.f, vc));
        float vf = (xf - smean[16 + d]) * sscale[16 + d];
        vf = fminf(10.f, fmaxf(-10.f, vf));
        tc += vc; tf += vf;
    }
#pragma unroll
    for (int d = 0; d < D; ++d)                  // coalesced per-d across wave
        xcrdT[((size_t)b * D + d) * N + nn] = row[d];
    sq[t] = s; Tc[t] = tc; Tf[t] = tf;
}

// ---------------------------------------------------------------------------
// K2: ROUND-14 -- round-11 PROVEN structure (block = 4 waves = 8 queries,
// sync-staged 16 KB panel tiles, per-wave round-8 2-query pipeline) with an
// INSTRUCTION DIET (all bit-identical):
//  (1) paired-j fill: j and j+1 computed jointly; the two ds_reads per d
//      are 256 B apart -> DS-combiner merges to ds_read2_b32.  Fill DS ops
//      512 -> 256 per wave.
//  (2) sq staged per tile (sqt[256]) -> removes 32 global loads + 64-bit
//      addressing per wave.
//  (3) matvec reads the float4-interleaved W layout: 2 dwordx4 per k
//      instead of 8 dwords (VMEM 256 -> 64 per wave).
// Distances, partition m=j*64+lane, keys, output: bit-identical to r8/r11.
// Spill tripwire: WRITE_SIZE must stay 16384 KB.
// ---------------------------------------------------------------------------
#define WAVE_LDS_FENCE() do {                                   \
    asm volatile("s_waitcnt lgkmcnt(0)" ::: "memory");          \
    __builtin_amdgcn_sched_barrier(0);                          \
} while (0)

__global__ __launch_bounds__(256) void knn_main(
    const float* __restrict__ xcrdT, const float* __restrict__ sq,
    const float* __restrict__ Tc, const float* __restrict__ Tf,
    const float* __restrict__ WcT, const float* __restrict__ WfT,
    const float* __restrict__ cbias, float* __restrict__ out)
{
    __shared__ float tile[D][256];               // 16 KB panel tile
    __shared__ float sqt[256];                   // staged sq for this tile
    __shared__ unsigned long long collect[8][CAP];
    __shared__ int sortedm[8][KNN];
    __shared__ float akbk[8][KNN][2];            // [q-slot][k][{a,b}]

    const int tid  = threadIdx.x;
    const int lane = tid & 63;
    const int wid  = tid >> 6;
    const int qid0 = blockIdx.x * 8 + wid * 2;   // even
    const int b  = qid0 >> 11;
    const int n0 = qid0 & (N - 1);
    const int n1 = n0 + 1;
    const int c0 = wid * 2, c1 = c0 + 1;         // this wave's LDS slots

    const float* xbT = xcrdT + (size_t)b * D * N;
    const float* sqb = sq + b * N;

    // two query rows (adjacent -> float2)
    float qx0[D], qx1[D];
#pragma unroll
    for (int d = 0; d < D; ++d) {
        float2 v = *(const float2*)(xbT + (size_t)d * N + n0);
        qx0[d] = v.x; qx1[d] = v.y;
    }
    const float sqn0 = sqb[n0], sqn1 = sqb[n1];

    // ---- fill: 8 staged tiles, paired-j compute from LDS ----
    float orig0[KNN], orig1[KNN];
    float vm0 = 1e30f, vm1 = 1e30f;
#pragma unroll
    for (int t = 0; t < 8; ++t) {
        __syncthreads();                         // previous tile fully consumed
        {
            const float* src = xbT + (size_t)(wid * 4) * N + t * 256 + lane * 4;
#pragma unroll
            for (int dd = 0; dd < 4; ++dd) {
                float4 v = *(const float4*)(src + (size_t)dd * N);
                *(float4*)&tile[wid * 4 + dd][lane * 4] = v;
            }
            if (tid < 64)
                *(float4*)&sqt[tid * 4] = *(const float4*)(sqb + t * 256 + tid * 4);
        }
        __syncthreads();                         // tile ready for all waves
#pragma unroll
        for (int jp = 0; jp < 2; ++jp) {
            const int j0  = t * 4 + jp * 2;      // same j order as round 8
            const int ml0 = (jp * 2) * 64 + lane;
            const int ml1 = ml0 + 64;
            float dA0 = 0.f, dA1 = 0.f, dB0 = 0.f, dB1 = 0.f;
#pragma unroll
            for (int d = 0; d < D; ++d) {
                float va = tile[d][ml0];         // 256 B apart -> ds_read2_b32
                float vb = tile[d][ml1];
                dA0 += qx0[d] * va; dA1 += qx1[d] * va;
                dB0 += qx0[d] * vb; dB1 += qx1[d] * vb;
            }
            float smA = sqt[ml0], smB = sqt[ml1];
            float oA0 = fabsf(sqrtf(fmaxf(sqn0 + smA - 2.0f * dA0, 0.f)));
            float oA1 = fabsf(sqrtf(fmaxf(sqn1 + smA - 2.0f * dA1, 0.f)));
            float oB0 = fabsf(sqrtf(fmaxf(sqn0 + smB - 2.0f * dB0, 0.f)));
            float oB1 = fabsf(sqrtf(fmaxf(sqn1 + smB - 2.0f * dB1, 0.f)));
            orig0[j0]     = oA0; orig1[j0]     = oA1;
            orig0[j0 + 1] = oB0; orig1[j0 + 1] = oB1;
            vm0 = fminf(fminf(vm0, oA0), oB0);
            vm1 = fminf(fminf(vm1, oA1), oB1);
        }
    }

    // ---- approx tau per query: 32nd-smallest of the 64 per-lane minima ----
#pragma unroll
    for (int k = 2; k <= 64; k <<= 1) {
#pragma unroll
        for (int j = k >> 1; j >= 1; j >>= 1) {
            float o0 = __shfl_xor(vm0, j, 64);
            float o1 = __shfl_xor(vm1, j, 64);
            bool lower = (lane & j) == 0;
            bool up    = (lane & k) == 0;
            vm0 = (lower == up) ? fminf(vm0, o0) : fmaxf(vm0, o0);
            vm1 = (lower == up) ? fminf(vm1, o1) : fmaxf(vm1, o1);
        }
    }
    const float tau0 = __shfl(vm0, 31, 64);      // >= exact 32nd smallest (q0)
    const float tau1 = __shfl(vm1, 31, 64);      // >= exact 32nd smallest (q1)

    // ---- tie-fixup compact, per query (wave-private LDS slice) ----
    const unsigned long long lmask = (1ULL << lane) - 1ULL;
    int T0, T1;
    {
        int base = 0;
#pragma unroll
        for (int j = 0; j < KNN; ++j) {
            bool f = (orig0[j] <= tau0);
            unsigned long long mk = __ballot(f);
            if (f) {
                int pos = base + (int)__popcll(mk & lmask);
                if (pos < CAP)
                    collect[c0][pos] =
                        (((unsigned long long)__float_as_uint(orig0[j])) << 11)
                        | (unsigned)(j * 64 + lane);
            }
            base += (int)__popcll(mk);
        }
        T0 = base < CAP ? base : CAP;
    }
    {
        int base = 0;
#pragma unroll
        for (int j = 0; j < KNN; ++j) {
            bool f = (orig1[j] <= tau1);
            unsigned long long mk = __ballot(f);
            if (f) {
                int pos = base + (int)__popcll(mk & lmask);
                if (pos < CAP)
                    collect[c1][pos] =
                        (((unsigned long long)__float_as_uint(orig1[j])) << 11)
                        | (unsigned)(j * 64 + lane);
            }
            base += (int)__popcll(mk);
        }
        T1 = base < CAP ? base : CAP;
    }
    WAVE_LDS_FENCE();                            // own-wave ds_writes drained

    if (T0 <= 64 && T1 <= 64) {
        // ---- fast path: two interleaved in-wave 64-key bitonic sorts ----
        unsigned long long key0 = (lane < T0) ? collect[c0][lane] : ~0ULL;
        unsigned long long key1 = (lane < T1) ? collect[c1][lane] : ~0ULL;
#pragma unroll
        for (int k = 2; k <= 64; k <<= 1) {
#pragma unroll
            for (int j = k >> 1; j >= 1; j >>= 1) {
                unsigned long long o0 = __shfl_xor(key0, j, 64);
                unsigned long long o1 = __shfl_xor(key1, j, 64);
                bool lower = (lane & j) == 0;
                bool up    = (lane & k) == 0;
                unsigned long long mn0 = (o0 < key0) ? o0 : key0;
                unsigned long long mx0 = (o0 < key0) ? key0 : o0;
                unsigned long long mn1 = (o1 < key1) ? o1 : key1;
                unsigned long long mx1 = (o1 < key1) ? key1 : o1;
                key0 = (lower == up) ? mn0 : mx0;
                key1 = (lower == up) ? mn1 : mx1;
            }
        }
        if (lane < KNN) {
            sortedm[c0][lane] = (int)(key0 & 2047u);
            sortedm[c1][lane] = (int)(key1 & 2047u);
        }
    } else {
        // ---- rare path: per-query fast/slow handling ----
#pragma unroll 1
        for (int q = 0; q < 2; ++q) {
            int T = q ? T1 : T0;
            unsigned long long* co = collect[q ? c1 : c0];
            int* so = sortedm[q ? c1 : c0];
            if (T <= 64) {
                unsigned long long key = (lane < T) ? co[lane] : ~0ULL;
#pragma unroll
                for (int k = 2; k <= 64; k <<= 1) {
#pragma unroll
                    for (int j = k >> 1; j >= 1; j >>= 1) {
                        unsigned long long o = __shfl_xor(key, j, 64);
                        bool lower = (lane & j) == 0;
                        bool up    = (lane & k) == 0;
                        unsigned long long mn = (o < key) ? o : key;
                        unsigned long long mx = (o < key) ? key : o;
                        key = (lower == up) ? mn : mx;
                    }
                }
                if (lane < KNN) so[lane] = (int)(key & 2047u);
            } else {
#pragma unroll 1
                for (int slot = 0; slot < CAP / 64; ++slot) {
                    int i = lane + slot * 64;
                    if (i < T) {
                        unsigned long long mk = co[i];
                        int rank = 0;
#pragma unroll 4
                        for (int t2 = 0; t2 < T; ++t2)
                            rank += (co[t2] < mk) ? 1 : 0;
                        if (rank < KNN) so[rank] = (int)(mk & 2047u);
                    }
                }
            }
        }
    }
    WAVE_LDS_FENCE();                            // sortedm visible to own wave

    // ---- gather ak/bk lane-parallel: lane = (q,k) ----
    const float* Tcb = Tc + b * N;
    const float* Tfb = Tf + b * N;
    {
        const float Tcn0 = Tcb[n0], Tfn0 = Tfb[n0];
        const float Tcn1 = Tcb[n1], Tfn1 = Tfb[n1];
        int q = lane >> 5;                       // 0 or 1
        int k = lane & 31;
        int wm = sortedm[c0 + q][k];
        float av = Tcb[wm] - (q ? Tcn1 : Tcn0);
        float bv = Tfb[wm] - (q ? Tfn1 : Tfn0);
        akbk[c0 + q][k][0] = av;
        akbk[c0 + q][k][1] = bv;
    }
    WAVE_LDS_FENCE();                            // akbk visible to own wave

    // ---- matvec: interleaved-float4 W loads shared by both queries ----
    float acc0[4] = {0.f, 0.f, 0.f, 0.f};
    float acc1[4] = {0.f, 0.f, 0.f, 0.f};

#pragma unroll
    for (int k = 0; k < KNN; ++k) {
        float ak0 = akbk[c0][k][0], bk0 = akbk[c0][k][1];
        float ak1 = akbk[c1][k][0], bk1 = akbk[c1][k][1];
        float4 wc4 = *(const float4*)(WcT + k * DM + lane * 4);
        float4 wf4 = *(const float4*)(WfT + k * DM + lane * 4);
        const float* wcp = (const float*)&wc4;
        const float* wfp = (const float*)&wf4;
#pragma unroll
        for (int q = 0; q < 4; ++q) {
            acc0[q] += wcp[q] * ak0 + wfp[q] * bk0;
            acc1[q] += wcp[q] * ak1 + wfp[q] * bk1;
        }
    }

    size_t ob0 = (size_t)qid0 * DM + lane;
#pragma unroll
    for (int q = 0; q < 4; ++q) {
        float cb = cbias[lane + q * 64];
        out[ob0 + q * 64]      = acc0[q] + cb;
        out[ob0 + DM + q * 64] = acc1[q] + cb;
    }
}

// ---------------------------------------------------------------------------
extern "C" void kernel_launch(void* const* d_in, const int* in_sizes, int n_in,
                              void* d_out, int out_size, void* d_ws, size_t ws_size,
                              hipStream_t stream)
{
    const float* x        = (const float*)d_in[0];   // (B,N,D)
    const float* features = (const float*)d_in[1];   // (B,D)
    const float* W_crd    = (const float*)d_in[2];   // (DM,K)
    const float* W_ftr    = (const float*)d_in[3];   // (DM,K)
    const float* pe_crd   = (const float*)d_in[4];   // (1,1,D,DM)
    const float* pe_ftr   = (const float*)d_in[5];   // (1,1,D,DM)
    // d_in[6] = k (constant 32), ignored

    float* out = (float*)d_out;                      // B*N*DM floats + 1 (pe_loss)

    float* xcrdT = (float*)d_ws;                     // 262144 (B*D*N, transposed)
    float* sqv   = xcrdT + (size_t)B * N * D;        // 16384
    float* Tc    = sqv  + B * N;                     // 16384
    float* Tf    = Tc   + B * N;                     // 16384
    float* cbias = Tf   + B * N;                     // 256
    float* WcT   = cbias + DM;                       // 8192 (float4-interleaved)
    float* WfT   = WcT + KNN * DM;                   // 8192 (float4-interleaved)

    knn_prep<<<65, 256, 0, stream>>>(x, features, W_crd, W_ftr, pe_crd, pe_ftr,
                                     xcrdT, sqv, Tc, Tf, WcT, WfT, cbias,
                                     out + (size_t)out_size - 1);
    knn_main<<<(B * N) / 8, 256, 0, stream>>>(xcrdT, sqv, Tc, Tf,
                                              WcT, WfT, cbias, out);
}